// Round 1
// baseline (4334.795 us; speedup 1.0000x reference)
//
#include <hip/hip_runtime.h>

#define NN 50000
#define NE 800000
#define DIM 128

// ---------------- SpMM: prop[row] += vals[e] * h[col], atomic scatter ----------------
// One 32-lane half-wave per edge; each lane handles a float4 (32*4 = 128 dims).
__global__ __launch_bounds__(256) void spmm_atomic(
    const int* __restrict__ ei, const float* __restrict__ vals,
    const float* __restrict__ h, float* __restrict__ prop) {
  const int lane32 = threadIdx.x & 31;
  int hw = blockIdx.x * (blockDim.x >> 5) + (threadIdx.x >> 5);
  const int stride = gridDim.x * (blockDim.x >> 5);
  for (int e = hw; e < NE; e += stride) {
    int r = ei[e];          // edge_index[0][e]
    int c = ei[NE + e];     // edge_index[1][e]
    float v = vals[e];
    if ((unsigned)r >= NN || (unsigned)c >= NN) continue;  // dtype-surprise guard
    float4 x = ((const float4*)(h + (size_t)c * DIM))[lane32];
    float* pp = prop + (size_t)r * DIM + lane32 * 4;
    unsafeAtomicAdd(pp + 0, v * x.x);   // native global_atomic_add_f32
    unsafeAtomicAdd(pp + 1, v * x.y);
    unsafeAtomicAdd(pp + 2, v * x.z);
    unsafeAtomicAdd(pp + 3, v * x.w);
  }
}

// ---------------- Dense layer: out = prop @ W + b, optional ReLU + L2 row-norm --------
// W staged in LDS; 256 threads -> ROWS=256/OUT_DIM rows per iteration,
// one thread per output element, k-loop over LDS.
template <int OUT_DIM, bool NORM>
__global__ __launch_bounds__(256) void layer_gemm(
    const float* __restrict__ prop, const float* __restrict__ W,
    const float* __restrict__ b, float* __restrict__ out, int n) {
  constexpr int ROWS = 256 / OUT_DIM;
  __shared__ float sW[DIM * OUT_DIM];
  __shared__ float sb[OUT_DIM];
  __shared__ float srow[ROWS][DIM];
  __shared__ float sred[ROWS][2];

  for (int i = threadIdx.x; i < DIM * OUT_DIM; i += 256) sW[i] = W[i];
  if (threadIdx.x < OUT_DIM) sb[threadIdx.x] = b[threadIdx.x];

  const int r = threadIdx.x / OUT_DIM;   // row within group (wave-uniform)
  const int j = threadIdx.x % OUT_DIM;   // output column

  for (int base = blockIdx.x * ROWS; base < n; base += gridDim.x * ROWS) {
    __syncthreads();  // protects srow/sred reuse; also covers initial sW load
    for (int i = threadIdx.x; i < ROWS * DIM; i += 256) {
      int rr = i >> 7, kk = i & 127;
      int row = base + rr;
      srow[rr][kk] = (row < n) ? prop[(size_t)row * DIM + kk] : 0.f;
    }
    __syncthreads();
    float acc = sb[j];
#pragma unroll
    for (int k = 0; k < DIM; ++k)
      acc = fmaf(srow[r][k], sW[k * OUT_DIM + j], acc);  // srow: broadcast; sW: 2-way (free)
    int row = base + r;
    if (NORM) {
      float v = fmaxf(acc, 0.f);
      float s = v * v;
#pragma unroll
      for (int off = 32; off >= 1; off >>= 1) s += __shfl_xor(s, off, 64);
      int wid = threadIdx.x >> 6;                 // wave id 0..3
      if ((threadIdx.x & 63) == 0) sred[r][wid & 1] = s;
      __syncthreads();
      float nrm = fmaxf(sqrtf(sred[r][0] + sred[r][1]), 1e-12f);
      if (row < n) out[(size_t)row * OUT_DIM + j] = v / nrm;
    } else {
      if (row < n) out[(size_t)row * OUT_DIM + j] = acc;
    }
  }
}

extern "C" void kernel_launch(void* const* d_in, const int* in_sizes, int n_in,
                              void* d_out, int out_size, void* d_ws, size_t ws_size,
                              hipStream_t stream) {
  const float* x  = (const float*)d_in[0];
  const int*   ei = (const int*)d_in[1];   // edge_index [2, NE] (int32 per harness contract)
  const float* C  = (const float*)d_in[2];
  const float* W1 = (const float*)d_in[3];
  const float* b1 = (const float*)d_in[4];
  const float* W2 = (const float*)d_in[5];
  const float* b2 = (const float*)d_in[6];
  const float* W3 = (const float*)d_in[7];
  const float* b3 = (const float*)d_in[8];
  float* out = (float*)d_out;

  float* prop = (float*)d_ws;                       // [NN,128] fp32
  float* h    = prop + (size_t)NN * DIM;            // [NN,128] fp32
  const size_t propBytes = (size_t)NN * DIM * sizeof(float);

  const dim3 blk(256);
  const int spmmGrid = 4096;   // grid-stride, ~2 waves of blocks per CU
  const int gemmGrid = 2048;   // each block loads W into LDS once, strides rows

  // layer 1: x -> h
  hipMemsetAsync(prop, 0, propBytes, stream);
  spmm_atomic<<<spmmGrid, blk, 0, stream>>>(ei, C, x, prop);
  layer_gemm<128, true><<<gemmGrid, blk, 0, stream>>>(prop, W1, b1, h, NN);

  // layer 2: h -> h
  hipMemsetAsync(prop, 0, propBytes, stream);
  spmm_atomic<<<spmmGrid, blk, 0, stream>>>(ei, C, h, prop);
  layer_gemm<128, true><<<gemmGrid, blk, 0, stream>>>(prop, W2, b2, h, NN);

  // layer 3: h -> out (64 classes, no norm)
  hipMemsetAsync(prop, 0, propBytes, stream);
  spmm_atomic<<<spmmGrid, blk, 0, stream>>>(ei, C, h, prop);
  layer_gemm<64, false><<<gemmGrid, blk, 0, stream>>>(prop, W3, b3, out, NN);
}

// Round 2
// 618.284 us; speedup vs baseline: 7.0110x; 7.0110x over previous
//
#include <hip/hip_runtime.h>

#define NN 50000
#define NE 800000
#define DIM 128

// ================= CSR build (edge pattern reused for all 3 layers) =================
__global__ __launch_bounds__(256) void edge_histo(const int* __restrict__ ei,
                                                  int* __restrict__ cnt) {
  int e = blockIdx.x * 256 + threadIdx.x;
  if (e >= NE) return;
  int r = ei[e], c = ei[NE + e];
  if ((unsigned)r < NN && (unsigned)c < NN) atomicAdd(&cnt[r], 1);
}

// Exclusive prefix scan over 50K counts, single block of 1024 (simple; ~tens of us).
__global__ __launch_bounds__(1024) void scan50k(const int* __restrict__ cnt,
                                                int* __restrict__ rowStart,
                                                int* __restrict__ cursor) {
  __shared__ int buf[1024];
  int carry = 0;
  if (threadIdx.x == 0) rowStart[0] = 0;
  for (int base = 0; base < NN; base += 1024) {
    int i = base + threadIdx.x;
    int v = (i < NN) ? cnt[i] : 0;
    buf[threadIdx.x] = v;
    __syncthreads();
    for (int off = 1; off < 1024; off <<= 1) {
      int t = (threadIdx.x >= off) ? buf[threadIdx.x - off] : 0;
      __syncthreads();
      buf[threadIdx.x] += t;
      __syncthreads();
    }
    int inc = buf[threadIdx.x];
    if (i < NN) { rowStart[i + 1] = carry + inc; cursor[i] = carry + inc - v; }
    int tot = buf[1023];
    __syncthreads();
    carry += tot;
  }
}

// Scatter packed (col, val) into row-sorted order.
__global__ __launch_bounds__(256) void edge_scatter(const int* __restrict__ ei,
                                                    const float* __restrict__ vals,
                                                    int* __restrict__ cursor,
                                                    int2* __restrict__ cv) {
  int e = blockIdx.x * 256 + threadIdx.x;
  if (e >= NE) return;
  int r = ei[e], c = ei[NE + e];
  if ((unsigned)r >= NN || (unsigned)c >= NN) return;
  int pos = atomicAdd(&cursor[r], 1);
  cv[pos] = make_int2(c, __float_as_int(vals[e]));
}

// ============ SpMM gather: one 32-lane half-wave per row, regs accumulate ============
__global__ __launch_bounds__(256) void spmm_csr(const int* __restrict__ rowStart,
                                                const int2* __restrict__ cv,
                                                const float* __restrict__ h,
                                                float* __restrict__ prop) {
  const int lane = threadIdx.x & 31;
  const int r = blockIdx.x * 8 + (threadIdx.x >> 5);
  if (r >= NN) return;
  int p = rowStart[r], pend = rowStart[r + 1];
  float4 acc = make_float4(0.f, 0.f, 0.f, 0.f);
  // unroll-2: two independent float4 gathers in flight
  for (; p + 1 < pend; p += 2) {
    int2 cv0 = cv[p], cv1 = cv[p + 1];
    float v0 = __int_as_float(cv0.y), v1 = __int_as_float(cv1.y);
    float4 x0 = ((const float4*)(h + (size_t)cv0.x * DIM))[lane];
    float4 x1 = ((const float4*)(h + (size_t)cv1.x * DIM))[lane];
    acc.x = fmaf(v0, x0.x, acc.x); acc.y = fmaf(v0, x0.y, acc.y);
    acc.z = fmaf(v0, x0.z, acc.z); acc.w = fmaf(v0, x0.w, acc.w);
    acc.x = fmaf(v1, x1.x, acc.x); acc.y = fmaf(v1, x1.y, acc.y);
    acc.z = fmaf(v1, x1.z, acc.z); acc.w = fmaf(v1, x1.w, acc.w);
  }
  if (p < pend) {
    int2 cv0 = cv[p];
    float v0 = __int_as_float(cv0.y);
    float4 x0 = ((const float4*)(h + (size_t)cv0.x * DIM))[lane];
    acc.x = fmaf(v0, x0.x, acc.x); acc.y = fmaf(v0, x0.y, acc.y);
    acc.z = fmaf(v0, x0.z, acc.z); acc.w = fmaf(v0, x0.w, acc.w);
  }
  ((float4*)(prop + (size_t)r * DIM))[lane] = acc;
}

// ---------------- fallback: atomic scatter SpMM (if ws too small) ----------------
__global__ __launch_bounds__(256) void spmm_atomic(
    const int* __restrict__ ei, const float* __restrict__ vals,
    const float* __restrict__ h, float* __restrict__ prop) {
  const int lane32 = threadIdx.x & 31;
  int hw = blockIdx.x * (blockDim.x >> 5) + (threadIdx.x >> 5);
  const int stride = gridDim.x * (blockDim.x >> 5);
  for (int e = hw; e < NE; e += stride) {
    int r = ei[e], c = ei[NE + e];
    float v = vals[e];
    if ((unsigned)r >= NN || (unsigned)c >= NN) continue;
    float4 x = ((const float4*)(h + (size_t)c * DIM))[lane32];
    float* pp = prop + (size_t)r * DIM + lane32 * 4;
    unsafeAtomicAdd(pp + 0, v * x.x);
    unsafeAtomicAdd(pp + 1, v * x.y);
    unsafeAtomicAdd(pp + 2, v * x.z);
    unsafeAtomicAdd(pp + 3, v * x.w);
  }
}

// ---------------- Dense layer: out = prop @ W + b, optional ReLU + L2 row-norm --------
template <int OUT_DIM, bool NORM>
__global__ __launch_bounds__(256) void layer_gemm(
    const float* __restrict__ prop, const float* __restrict__ W,
    const float* __restrict__ b, float* __restrict__ out, int n) {
  constexpr int ROWS = 256 / OUT_DIM;
  __shared__ float sW[DIM * OUT_DIM];
  __shared__ float sb[OUT_DIM];
  __shared__ float srow[ROWS][DIM];
  __shared__ float sred[ROWS][2];

  for (int i = threadIdx.x; i < DIM * OUT_DIM; i += 256) sW[i] = W[i];
  if (threadIdx.x < OUT_DIM) sb[threadIdx.x] = b[threadIdx.x];

  const int r = threadIdx.x / OUT_DIM;
  const int j = threadIdx.x % OUT_DIM;

  for (int base = blockIdx.x * ROWS; base < n; base += gridDim.x * ROWS) {
    __syncthreads();
    for (int i = threadIdx.x; i < ROWS * DIM; i += 256) {
      int rr = i >> 7, kk = i & 127;
      int row = base + rr;
      srow[rr][kk] = (row < n) ? prop[(size_t)row * DIM + kk] : 0.f;
    }
    __syncthreads();
    float acc = sb[j];
#pragma unroll
    for (int k = 0; k < DIM; ++k)
      acc = fmaf(srow[r][k], sW[k * OUT_DIM + j], acc);
    int row = base + r;
    if (NORM) {
      float v = fmaxf(acc, 0.f);
      float s = v * v;
#pragma unroll
      for (int off = 32; off >= 1; off >>= 1) s += __shfl_xor(s, off, 64);
      int wid = threadIdx.x >> 6;
      if ((threadIdx.x & 63) == 0) sred[r][wid & 1] = s;
      __syncthreads();
      float nrm = fmaxf(sqrtf(sred[r][0] + sred[r][1]), 1e-12f);
      if (row < n) out[(size_t)row * OUT_DIM + j] = v / nrm;
    } else {
      if (row < n) out[(size_t)row * OUT_DIM + j] = acc;
    }
  }
}

extern "C" void kernel_launch(void* const* d_in, const int* in_sizes, int n_in,
                              void* d_out, int out_size, void* d_ws, size_t ws_size,
                              hipStream_t stream) {
  const float* x  = (const float*)d_in[0];
  const int*   ei = (const int*)d_in[1];
  const float* C  = (const float*)d_in[2];
  const float* W1 = (const float*)d_in[3];
  const float* b1 = (const float*)d_in[4];
  const float* W2 = (const float*)d_in[5];
  const float* b2 = (const float*)d_in[6];
  const float* W3 = (const float*)d_in[7];
  const float* b3 = (const float*)d_in[8];
  float* out = (float*)d_out;

  // ---- workspace layout ----
  float* prop     = (float*)d_ws;                        // NN*DIM f32
  float* h        = prop + (size_t)NN * DIM;             // NN*DIM f32
  int*   rowStart = (int*)(h + (size_t)NN * DIM);        // NN+1 (+1 pad for 8B align)
  int*   cnt      = rowStart + NN + 2;                   // NN
  int*   cursor   = cnt + NN;                            // NN
  int2*  cv       = (int2*)(cursor + NN);                // NE packed (col,val)
  const size_t need = (size_t)(2 * NN * DIM) * 4 + (size_t)(3 * NN + 2) * 4 + (size_t)NE * 8;

  const dim3 blk(256);
  const int gemmGrid = 2048;

  if (ws_size >= need) {
    // ---- build CSR once, reuse 3x ----
    hipMemsetAsync(cnt, 0, (size_t)NN * 4, stream);
    edge_histo<<<(NE + 255) / 256, blk, 0, stream>>>(ei, cnt);
    scan50k<<<1, 1024, 0, stream>>>(cnt, rowStart, cursor);
    edge_scatter<<<(NE + 255) / 256, blk, 0, stream>>>(ei, C, cursor, cv);

    const int spmmGrid = (NN + 7) / 8;
    spmm_csr<<<spmmGrid, blk, 0, stream>>>(rowStart, cv, x, prop);
    layer_gemm<128, true><<<gemmGrid, blk, 0, stream>>>(prop, W1, b1, h, NN);
    spmm_csr<<<spmmGrid, blk, 0, stream>>>(rowStart, cv, h, prop);
    layer_gemm<128, true><<<gemmGrid, blk, 0, stream>>>(prop, W2, b2, h, NN);
    spmm_csr<<<spmmGrid, blk, 0, stream>>>(rowStart, cv, h, prop);
    layer_gemm<64, false><<<gemmGrid, blk, 0, stream>>>(prop, W3, b3, out, NN);
  } else {
    // fallback: atomic path
    const size_t propBytes = (size_t)NN * DIM * sizeof(float);
    const int spmmGrid = 4096;
    hipMemsetAsync(prop, 0, propBytes, stream);
    spmm_atomic<<<spmmGrid, blk, 0, stream>>>(ei, C, x, prop);
    layer_gemm<128, true><<<gemmGrid, blk, 0, stream>>>(prop, W1, b1, h, NN);
    hipMemsetAsync(prop, 0, propBytes, stream);
    spmm_atomic<<<spmmGrid, blk, 0, stream>>>(ei, C, h, prop);
    layer_gemm<128, true><<<gemmGrid, blk, 0, stream>>>(prop, W2, b2, h, NN);
    hipMemsetAsync(prop, 0, propBytes, stream);
    spmm_atomic<<<spmmGrid, blk, 0, stream>>>(ei, C, h, prop);
    layer_gemm<64, false><<<gemmGrid, blk, 0, stream>>>(prop, W3, b3, out, NN);
  }
}

// Round 3
// 518.328 us; speedup vs baseline: 8.3630x; 1.1928x over previous
//
#include <hip/hip_runtime.h>

#define NN 50000
#define NE 800000
#define DIM 128

// ================= CSR build (edge pattern reused for all 3 layers) =================
__global__ __launch_bounds__(256) void edge_histo(const int* __restrict__ ei,
                                                  int* __restrict__ cnt) {
  int e = blockIdx.x * 256 + threadIdx.x;
  if (e >= NE) return;
  int r = ei[e], c = ei[NE + e];
  if ((unsigned)r < NN && (unsigned)c < NN) atomicAdd(&cnt[r], 1);
}

// Exclusive scan of 50K counts: chunk-per-thread + single block scan (2 syncs).
__global__ __launch_bounds__(1024) void scan_csr(const int* __restrict__ cnt,
                                                 int* __restrict__ rowStart,
                                                 int* __restrict__ cursor) {
  constexpr int C = (NN + 1023) / 1024;  // 49
  const int t = threadIdx.x;
  const int i0 = t * C, i1 = (i0 + C < NN) ? i0 + C : NN;
  int s = 0;
  for (int i = i0; i < i1; ++i) s += cnt[i];
  // block exclusive scan of per-thread sums
  const int lane = t & 63, wid = t >> 6;  // 16 waves
  int v = s;
  for (int off = 1; off < 64; off <<= 1) {
    int u = __shfl_up(v, off, 64);
    if (lane >= off) v += u;
  }
  __shared__ int wsum[16], wbase[16];
  if (lane == 63) wsum[wid] = v;
  __syncthreads();
  if (t == 0) { int run = 0; for (int w = 0; w < 16; ++w) { wbase[w] = run; run += wsum[w]; } }
  __syncthreads();
  int run = wbase[wid] + (v - s);   // exclusive prefix for this thread's chunk
  for (int i = i0; i < i1; ++i) { rowStart[i] = run; cursor[i] = run; run += cnt[i]; }
  if (t == 1023) rowStart[NN] = run;  // t=1023's chunk is empty/last -> run == total
}

// Scatter packed (col, val) into row-sorted order.
__global__ __launch_bounds__(256) void edge_scatter(const int* __restrict__ ei,
                                                    const float* __restrict__ vals,
                                                    int* __restrict__ cursor,
                                                    int2* __restrict__ cv) {
  int e = blockIdx.x * 256 + threadIdx.x;
  if (e >= NE) return;
  int r = ei[e], c = ei[NE + e];
  if ((unsigned)r >= NN || (unsigned)c >= NN) return;
  int pos = atomicAdd(&cursor[r], 1);
  cv[pos] = make_int2(c, __float_as_int(vals[e]));
}

// ============ SpMM gather: D/4 lanes per row, regs accumulate, no atomics ============
template <int D, bool BIAS>
__global__ __launch_bounds__(256) void spmm_csr(const int* __restrict__ rowStart,
                                                const int2* __restrict__ cv,
                                                const float* __restrict__ h,
                                                const float* __restrict__ bias,
                                                float* __restrict__ out) {
  constexpr int L = D / 4;                      // lanes per row
  const int lane = threadIdx.x % L;
  const int r = blockIdx.x * (256 / L) + threadIdx.x / L;
  if (r >= NN) return;
  int p = rowStart[r], pend = rowStart[r + 1];
  float4 acc = BIAS ? ((const float4*)bias)[lane] : make_float4(0.f, 0.f, 0.f, 0.f);
  for (; p + 1 < pend; p += 2) {
    int2 cv0 = cv[p], cv1 = cv[p + 1];
    float v0 = __int_as_float(cv0.y), v1 = __int_as_float(cv1.y);
    float4 x0 = ((const float4*)(h + (size_t)cv0.x * D))[lane];
    float4 x1 = ((const float4*)(h + (size_t)cv1.x * D))[lane];
    acc.x = fmaf(v0, x0.x, acc.x); acc.y = fmaf(v0, x0.y, acc.y);
    acc.z = fmaf(v0, x0.z, acc.z); acc.w = fmaf(v0, x0.w, acc.w);
    acc.x = fmaf(v1, x1.x, acc.x); acc.y = fmaf(v1, x1.y, acc.y);
    acc.z = fmaf(v1, x1.z, acc.z); acc.w = fmaf(v1, x1.w, acc.w);
  }
  if (p < pend) {
    int2 cv0 = cv[p];
    float v0 = __int_as_float(cv0.y);
    float4 x0 = ((const float4*)(h + (size_t)cv0.x * D))[lane];
    acc.x = fmaf(v0, x0.x, acc.x); acc.y = fmaf(v0, x0.y, acc.y);
    acc.z = fmaf(v0, x0.z, acc.z); acc.w = fmaf(v0, x0.w, acc.w);
  }
  ((float4*)(out + (size_t)r * D))[lane] = acc;
}

// ---------------- fallback: atomic scatter SpMM (if ws too small) ----------------
__global__ __launch_bounds__(256) void spmm_atomic(
    const int* __restrict__ ei, const float* __restrict__ vals,
    const float* __restrict__ h, float* __restrict__ prop) {
  const int lane32 = threadIdx.x & 31;
  int hw = blockIdx.x * (blockDim.x >> 5) + (threadIdx.x >> 5);
  const int stride = gridDim.x * (blockDim.x >> 5);
  for (int e = hw; e < NE; e += stride) {
    int r = ei[e], c = ei[NE + e];
    float v = vals[e];
    if ((unsigned)r >= NN || (unsigned)c >= NN) continue;
    float4 x = ((const float4*)(h + (size_t)c * DIM))[lane32];
    float* pp = prop + (size_t)r * DIM + lane32 * 4;
    unsafeAtomicAdd(pp + 0, v * x.x);
    unsafeAtomicAdd(pp + 1, v * x.y);
    unsafeAtomicAdd(pp + 2, v * x.z);
    unsafeAtomicAdd(pp + 3, v * x.w);
  }
}

// ========== Register-tiled dense layer: out = A@W (+b) (+ReLU +L2 row-norm) ==========
// LDS-free. 256 threads = JT col-groups x RG row-groups; each thread: MR rows x 4 cols.
// A loads broadcast within wave (same addr across JT lanes); W loads coalesced, L2-hot.
template <int OUT_DIM, bool NORM, bool BIAS>
__global__ __launch_bounds__(256) void gemm_rt(
    const float* __restrict__ A, const float* __restrict__ W,
    const float* __restrict__ b, float* __restrict__ out, int n) {
  constexpr int JT = OUT_DIM / 4;     // threads along N (32 or 16)
  constexpr int RG = 256 / JT;        // row groups (8 or 16)
  constexpr int MR = 8;               // rows per thread
  constexpr int TILE_M = RG * MR;     // 64 or 128
  const int j  = threadIdx.x % JT;
  const int rg = threadIdx.x / JT;
  const int row0 = blockIdx.x * TILE_M + rg * MR;

  float4 bv = make_float4(0.f, 0.f, 0.f, 0.f);
  if (BIAS) bv = ((const float4*)b)[j];

  float acc[MR][4];
#pragma unroll
  for (int i = 0; i < MR; ++i) {
    acc[i][0] = bv.x; acc[i][1] = bv.y; acc[i][2] = bv.z; acc[i][3] = bv.w;
  }
  const float* Arow[MR];
#pragma unroll
  for (int i = 0; i < MR; ++i) {
    int r = row0 + i; if (r > n - 1) r = n - 1;   // clamp; tail rows not stored
    Arow[i] = A + (size_t)r * DIM;
  }

#pragma unroll 2
  for (int kk = 0; kk < DIM; kk += 4) {
    float4 w0 = *(const float4*)(W + (size_t)(kk + 0) * OUT_DIM + j * 4);
    float4 w1 = *(const float4*)(W + (size_t)(kk + 1) * OUT_DIM + j * 4);
    float4 w2 = *(const float4*)(W + (size_t)(kk + 2) * OUT_DIM + j * 4);
    float4 w3 = *(const float4*)(W + (size_t)(kk + 3) * OUT_DIM + j * 4);
    float4 a4[MR];
#pragma unroll
    for (int i = 0; i < MR; ++i) a4[i] = *(const float4*)(Arow[i] + kk);
#pragma unroll
    for (int i = 0; i < MR; ++i) {
      acc[i][0] = fmaf(a4[i].x, w0.x, acc[i][0]);
      acc[i][1] = fmaf(a4[i].x, w0.y, acc[i][1]);
      acc[i][2] = fmaf(a4[i].x, w0.z, acc[i][2]);
      acc[i][3] = fmaf(a4[i].x, w0.w, acc[i][3]);
      acc[i][0] = fmaf(a4[i].y, w1.x, acc[i][0]);
      acc[i][1] = fmaf(a4[i].y, w1.y, acc[i][1]);
      acc[i][2] = fmaf(a4[i].y, w1.z, acc[i][2]);
      acc[i][3] = fmaf(a4[i].y, w1.w, acc[i][3]);
      acc[i][0] = fmaf(a4[i].z, w2.x, acc[i][0]);
      acc[i][1] = fmaf(a4[i].z, w2.y, acc[i][1]);
      acc[i][2] = fmaf(a4[i].z, w2.z, acc[i][2]);
      acc[i][3] = fmaf(a4[i].z, w2.w, acc[i][3]);
      acc[i][0] = fmaf(a4[i].w, w3.x, acc[i][0]);
      acc[i][1] = fmaf(a4[i].w, w3.y, acc[i][1]);
      acc[i][2] = fmaf(a4[i].w, w3.z, acc[i][2]);
      acc[i][3] = fmaf(a4[i].w, w3.w, acc[i][3]);
    }
  }

#pragma unroll
  for (int i = 0; i < MR; ++i) {
    int row = row0 + i;
    if (NORM) {
      float v0 = fmaxf(acc[i][0], 0.f), v1 = fmaxf(acc[i][1], 0.f);
      float v2 = fmaxf(acc[i][2], 0.f), v3 = fmaxf(acc[i][3], 0.f);
      float s = v0 * v0 + v1 * v1 + v2 * v2 + v3 * v3;
#pragma unroll
      for (int off = JT / 2; off >= 1; off >>= 1) s += __shfl_xor(s, off, JT);
      float inv = 1.0f / fmaxf(sqrtf(s), 1e-12f);
      if (row < n) {
        float4 st = make_float4(v0 * inv, v1 * inv, v2 * inv, v3 * inv);
        ((float4*)(out + (size_t)row * OUT_DIM))[j] = st;
      }
    } else {
      if (row < n) {
        float4 st = make_float4(acc[i][0], acc[i][1], acc[i][2], acc[i][3]);
        ((float4*)(out + (size_t)row * OUT_DIM))[j] = st;
      }
    }
  }
}

extern "C" void kernel_launch(void* const* d_in, const int* in_sizes, int n_in,
                              void* d_out, int out_size, void* d_ws, size_t ws_size,
                              hipStream_t stream) {
  const float* x  = (const float*)d_in[0];
  const int*   ei = (const int*)d_in[1];
  const float* C  = (const float*)d_in[2];
  const float* W1 = (const float*)d_in[3];
  const float* b1 = (const float*)d_in[4];
  const float* W2 = (const float*)d_in[5];
  const float* b2 = (const float*)d_in[6];
  const float* W3 = (const float*)d_in[7];
  const float* b3 = (const float*)d_in[8];
  float* out = (float*)d_out;

  // ---- workspace layout ----
  float* prop     = (float*)d_ws;                        // NN*DIM f32 (also g[NN*64])
  float* h        = prop + (size_t)NN * DIM;             // NN*DIM f32
  int*   rowStart = (int*)(h + (size_t)NN * DIM);        // NN+1 (+pad)
  int*   cnt      = rowStart + NN + 2;                   // NN
  int*   cursor   = cnt + NN;                            // NN
  int2*  cv       = (int2*)(cursor + NN);                // NE packed (col,val)
  const size_t need = (size_t)(2 * NN * DIM) * 4 + (size_t)(3 * NN + 2) * 4 + (size_t)NE * 8;

  const dim3 blk(256);
  const int g128 = (NN + 63) / 64;     // gemm_rt<128> tiles 64 rows
  const int g64  = (NN + 127) / 128;   // gemm_rt<64> tiles 128 rows

  if (ws_size >= need) {
    // ---- build CSR once, reuse 3x ----
    hipMemsetAsync(cnt, 0, (size_t)NN * 4, stream);
    edge_histo<<<(NE + 255) / 256, blk, 0, stream>>>(ei, cnt);
    scan_csr<<<1, 1024, 0, stream>>>(cnt, rowStart, cursor);
    edge_scatter<<<(NE + 255) / 256, blk, 0, stream>>>(ei, C, cursor, cv);

    // layer 1: prop = C@x; h = norm(relu(prop@W1 + b1))
    spmm_csr<128, false><<<(NN + 7) / 8, blk, 0, stream>>>(rowStart, cv, x, nullptr, prop);
    gemm_rt<128, true, true><<<g128, blk, 0, stream>>>(prop, W1, b1, h, NN);
    // layer 2
    spmm_csr<128, false><<<(NN + 7) / 8, blk, 0, stream>>>(rowStart, cv, h, nullptr, prop);
    gemm_rt<128, true, true><<<g128, blk, 0, stream>>>(prop, W2, b2, h, NN);
    // layer 3 reassociated: g = h@W3 (no bias); out = C@g + b3
    gemm_rt<64, false, false><<<g64, blk, 0, stream>>>(h, W3, nullptr, prop, NN);
    spmm_csr<64, true><<<(NN + 15) / 16, blk, 0, stream>>>(rowStart, cv, prop, b3, out);
  } else {
    // fallback: atomic scatter path
    const size_t propBytes = (size_t)NN * DIM * sizeof(float);
    const int spmmGrid = 4096;
    hipMemsetAsync(prop, 0, propBytes, stream);
    spmm_atomic<<<spmmGrid, blk, 0, stream>>>(ei, C, x, prop);
    gemm_rt<128, true, true><<<g128, blk, 0, stream>>>(prop, W1, b1, h, NN);
    hipMemsetAsync(prop, 0, propBytes, stream);
    spmm_atomic<<<spmmGrid, blk, 0, stream>>>(ei, C, h, prop);
    gemm_rt<128, true, true><<<g128, blk, 0, stream>>>(prop, W2, b2, h, NN);
    hipMemsetAsync(prop, 0, propBytes, stream);
    spmm_atomic<<<spmmGrid, blk, 0, stream>>>(ei, C, h, prop);
    gemm_rt<64, false, true><<<g64, blk, 0, stream>>>(prop, W3, b3, out, NN);
  }
}

// Round 5
// 414.453 us; speedup vs baseline: 10.4591x; 1.2506x over previous
//
#include <hip/hip_runtime.h>

#define NN 50000
#define NE 800000
#define DIM 128
#define NB ((NN + 255) / 256)   // 196 scan chunks

// ================= CSR build (edge pattern reused for all 3 layers) =================
__global__ __launch_bounds__(256) void edge_histo(const int* __restrict__ ei,
                                                  int* __restrict__ cnt) {
  int e = blockIdx.x * 256 + threadIdx.x;
  if (e >= NE) return;
  int r = ei[e], c = ei[NE + e];
  if ((unsigned)r < NN && (unsigned)c < NN) atomicAdd(&cnt[r], 1);
}

// ---- distributed 2-level exclusive scan (replaces the 109us single-block scan) ----
__global__ __launch_bounds__(256) void block_sums(const int* __restrict__ cnt,
                                                  int* __restrict__ bsum) {
  int i = blockIdx.x * 256 + threadIdx.x;
  int v = (i < NN) ? cnt[i] : 0;
#pragma unroll
  for (int off = 1; off < 64; off <<= 1) v += __shfl_xor(v, off, 64);
  __shared__ int ws[4];
  if ((threadIdx.x & 63) == 0) ws[threadIdx.x >> 6] = v;
  __syncthreads();
  if (threadIdx.x == 0) bsum[blockIdx.x] = ws[0] + ws[1] + ws[2] + ws[3];
}

__global__ __launch_bounds__(256) void scan_bsums(const int* __restrict__ bsum,
                                                  int* __restrict__ bbase) {
  int t = threadIdx.x;
  int v = (t < NB) ? bsum[t] : 0;
  int lane = t & 63, w = t >> 6;
  int inc = v;
#pragma unroll
  for (int off = 1; off < 64; off <<= 1) {
    int u = __shfl_up(inc, off, 64);
    if (lane >= off) inc += u;
  }
  __shared__ int ws[4];
  if (lane == 63) ws[w] = inc;
  __syncthreads();
  int wb = 0;
  for (int k = 0; k < w; ++k) wb += ws[k];
  if (t < NB) bbase[t] = wb + inc - v;
}

__global__ __launch_bounds__(256) void scan_final(const int* __restrict__ cnt,
                                                  const int* __restrict__ bbase,
                                                  int* __restrict__ rowStart,
                                                  int* __restrict__ cursor) {
  int i = blockIdx.x * 256 + threadIdx.x;
  int v = (i < NN) ? cnt[i] : 0;
  int lane = threadIdx.x & 63, w = threadIdx.x >> 6;
  int inc = v;
#pragma unroll
  for (int off = 1; off < 64; off <<= 1) {
    int u = __shfl_up(inc, off, 64);
    if (lane >= off) inc += u;
  }
  __shared__ int ws[4];
  if (lane == 63) ws[w] = inc;
  __syncthreads();
  int wb = 0;
  for (int k = 0; k < w; ++k) wb += ws[k];
  int ex = bbase[blockIdx.x] + wb + inc - v;   // global exclusive prefix
  if (i < NN) { rowStart[i] = ex; cursor[i] = ex; }
  if (i == NN - 1) rowStart[NN] = ex + v;
}

// Scatter packed (col, val) into row-sorted order.
__global__ __launch_bounds__(256) void edge_scatter(const int* __restrict__ ei,
                                                    const float* __restrict__ vals,
                                                    int* __restrict__ cursor,
                                                    int2* __restrict__ cv) {
  int e = blockIdx.x * 256 + threadIdx.x;
  if (e >= NE) return;
  int r = ei[e], c = ei[NE + e];
  if ((unsigned)r >= NN || (unsigned)c >= NN) return;
  int pos = atomicAdd(&cursor[r], 1);
  cv[pos] = make_int2(c, __float_as_int(vals[e]));
}

// ============ SpMM gather: D/4 lanes per row, regs accumulate, no atomics ============
template <int D, bool BIAS>
__global__ __launch_bounds__(256) void spmm_csr(const int* __restrict__ rowStart,
                                                const int2* __restrict__ cv,
                                                const float* __restrict__ h,
                                                const float* __restrict__ bias,
                                                float* __restrict__ out) {
  constexpr int L = D / 4;                      // lanes per row
  const int lane = threadIdx.x % L;
  const int r = blockIdx.x * (256 / L) + threadIdx.x / L;
  if (r >= NN) return;
  int p = rowStart[r], pend = rowStart[r + 1];
  float4 acc = BIAS ? ((const float4*)bias)[lane] : make_float4(0.f, 0.f, 0.f, 0.f);
  // unroll-4: four independent float4 gathers in flight
  for (; p + 3 < pend; p += 4) {
    int2 e0 = cv[p], e1 = cv[p + 1], e2 = cv[p + 2], e3 = cv[p + 3];
    float4 x0 = ((const float4*)(h + (size_t)e0.x * D))[lane];
    float4 x1 = ((const float4*)(h + (size_t)e1.x * D))[lane];
    float4 x2 = ((const float4*)(h + (size_t)e2.x * D))[lane];
    float4 x3 = ((const float4*)(h + (size_t)e3.x * D))[lane];
    float v0 = __int_as_float(e0.y), v1 = __int_as_float(e1.y);
    float v2 = __int_as_float(e2.y), v3 = __int_as_float(e3.y);
    acc.x = fmaf(v0, x0.x, acc.x); acc.y = fmaf(v0, x0.y, acc.y);
    acc.z = fmaf(v0, x0.z, acc.z); acc.w = fmaf(v0, x0.w, acc.w);
    acc.x = fmaf(v1, x1.x, acc.x); acc.y = fmaf(v1, x1.y, acc.y);
    acc.z = fmaf(v1, x1.z, acc.z); acc.w = fmaf(v1, x1.w, acc.w);
    acc.x = fmaf(v2, x2.x, acc.x); acc.y = fmaf(v2, x2.y, acc.y);
    acc.z = fmaf(v2, x2.z, acc.z); acc.w = fmaf(v2, x2.w, acc.w);
    acc.x = fmaf(v3, x3.x, acc.x); acc.y = fmaf(v3, x3.y, acc.y);
    acc.z = fmaf(v3, x3.z, acc.z); acc.w = fmaf(v3, x3.w, acc.w);
  }
  for (; p < pend; ++p) {
    int2 e0 = cv[p];
    float v0 = __int_as_float(e0.y);
    float4 x0 = ((const float4*)(h + (size_t)e0.x * D))[lane];
    acc.x = fmaf(v0, x0.x, acc.x); acc.y = fmaf(v0, x0.y, acc.y);
    acc.z = fmaf(v0, x0.z, acc.z); acc.w = fmaf(v0, x0.w, acc.w);
  }
  ((float4*)(out + (size_t)r * D))[lane] = acc;
}

// ---------------- fallback: atomic scatter SpMM (if ws too small) ----------------
__global__ __launch_bounds__(256) void spmm_atomic(
    const int* __restrict__ ei, const float* __restrict__ vals,
    const float* __restrict__ h, float* __restrict__ prop) {
  const int lane32 = threadIdx.x & 31;
  int hw = blockIdx.x * (blockDim.x >> 5) + (threadIdx.x >> 5);
  const int stride = gridDim.x * (blockDim.x >> 5);
  for (int e = hw; e < NE; e += stride) {
    int r = ei[e], c = ei[NE + e];
    float v = vals[e];
    if ((unsigned)r >= NN || (unsigned)c >= NN) continue;
    float4 x = ((const float4*)(h + (size_t)c * DIM))[lane32];
    float* pp = prop + (size_t)r * DIM + lane32 * 4;
    unsafeAtomicAdd(pp + 0, v * x.x);
    unsafeAtomicAdd(pp + 1, v * x.y);
    unsafeAtomicAdd(pp + 2, v * x.z);
    unsafeAtomicAdd(pp + 3, v * x.w);
  }
}

// ========== Register-tiled dense layer: out = A@W (+b) (+ReLU +L2 row-norm) ==========
template <int OUT_DIM, bool NORM, bool BIAS>
__global__ __launch_bounds__(256) void gemm_rt(
    const float* __restrict__ A, const float* __restrict__ W,
    const float* __restrict__ b, float* __restrict__ out, int n) {
  constexpr int JT = OUT_DIM / 4;
  constexpr int RG = 256 / JT;
  constexpr int MR = 8;
  constexpr int TILE_M = RG * MR;
  const int j  = threadIdx.x % JT;
  const int rg = threadIdx.x / JT;
  const int row0 = blockIdx.x * TILE_M + rg * MR;

  float4 bv = make_float4(0.f, 0.f, 0.f, 0.f);
  if (BIAS) bv = ((const float4*)b)[j];

  float acc[MR][4];
#pragma unroll
  for (int i = 0; i < MR; ++i) {
    acc[i][0] = bv.x; acc[i][1] = bv.y; acc[i][2] = bv.z; acc[i][3] = bv.w;
  }
  const float* Arow[MR];
#pragma unroll
  for (int i = 0; i < MR; ++i) {
    int r = row0 + i; if (r > n - 1) r = n - 1;
    Arow[i] = A + (size_t)r * DIM;
  }

#pragma unroll 2
  for (int kk = 0; kk < DIM; kk += 4) {
    float4 w0 = *(const float4*)(W + (size_t)(kk + 0) * OUT_DIM + j * 4);
    float4 w1 = *(const float4*)(W + (size_t)(kk + 1) * OUT_DIM + j * 4);
    float4 w2 = *(const float4*)(W + (size_t)(kk + 2) * OUT_DIM + j * 4);
    float4 w3 = *(const float4*)(W + (size_t)(kk + 3) * OUT_DIM + j * 4);
    float4 a4[MR];
#pragma unroll
    for (int i = 0; i < MR; ++i) a4[i] = *(const float4*)(Arow[i] + kk);
#pragma unroll
    for (int i = 0; i < MR; ++i) {
      acc[i][0] = fmaf(a4[i].x, w0.x, acc[i][0]);
      acc[i][1] = fmaf(a4[i].x, w0.y, acc[i][1]);
      acc[i][2] = fmaf(a4[i].x, w0.z, acc[i][2]);
      acc[i][3] = fmaf(a4[i].x, w0.w, acc[i][3]);
      acc[i][0] = fmaf(a4[i].y, w1.x, acc[i][0]);
      acc[i][1] = fmaf(a4[i].y, w1.y, acc[i][1]);
      acc[i][2] = fmaf(a4[i].y, w1.z, acc[i][2]);
      acc[i][3] = fmaf(a4[i].y, w1.w, acc[i][3]);
      acc[i][0] = fmaf(a4[i].z, w2.x, acc[i][0]);
      acc[i][1] = fmaf(a4[i].z, w2.y, acc[i][1]);
      acc[i][2] = fmaf(a4[i].z, w2.z, acc[i][2]);
      acc[i][3] = fmaf(a4[i].z, w2.w, acc[i][3]);
      acc[i][0] = fmaf(a4[i].w, w3.x, acc[i][0]);
      acc[i][1] = fmaf(a4[i].w, w3.y, acc[i][1]);
      acc[i][2] = fmaf(a4[i].w, w3.z, acc[i][2]);
      acc[i][3] = fmaf(a4[i].w, w3.w, acc[i][3]);
    }
  }

#pragma unroll
  for (int i = 0; i < MR; ++i) {
    int row = row0 + i;
    if (NORM) {
      float v0 = fmaxf(acc[i][0], 0.f), v1 = fmaxf(acc[i][1], 0.f);
      float v2 = fmaxf(acc[i][2], 0.f), v3 = fmaxf(acc[i][3], 0.f);
      float s = v0 * v0 + v1 * v1 + v2 * v2 + v3 * v3;
#pragma unroll
      for (int off = JT / 2; off >= 1; off >>= 1) s += __shfl_xor(s, off, JT);
      float inv = 1.0f / fmaxf(sqrtf(s), 1e-12f);
      if (row < n) {
        float4 st = make_float4(v0 * inv, v1 * inv, v2 * inv, v3 * inv);
        ((float4*)(out + (size_t)row * OUT_DIM))[j] = st;
      }
    } else {
      if (row < n) {
        float4 st = make_float4(acc[i][0], acc[i][1], acc[i][2], acc[i][3]);
        ((float4*)(out + (size_t)row * OUT_DIM))[j] = st;
      }
    }
  }
}

extern "C" void kernel_launch(void* const* d_in, const int* in_sizes, int n_in,
                              void* d_out, int out_size, void* d_ws, size_t ws_size,
                              hipStream_t stream) {
  const float* x  = (const float*)d_in[0];
  const int*   ei = (const int*)d_in[1];
  const float* C  = (const float*)d_in[2];
  const float* W1 = (const float*)d_in[3];
  const float* b1 = (const float*)d_in[4];
  const float* W2 = (const float*)d_in[5];
  const float* b2 = (const float*)d_in[6];
  const float* W3 = (const float*)d_in[7];
  const float* b3 = (const float*)d_in[8];
  float* out = (float*)d_out;

  // ---- workspace layout ----
  float* prop     = (float*)d_ws;                        // NN*DIM f32 (also g[NN*64])
  float* h        = prop + (size_t)NN * DIM;             // NN*DIM f32
  int*   rowStart = (int*)(h + (size_t)NN * DIM);        // NN+1 (+pad)
  int*   cnt      = rowStart + NN + 2;                   // NN
  int*   cursor   = cnt + NN;                            // NN
  int*   bsum     = cursor + NN;                         // 256
  int*   bbase    = bsum + 256;                          // 256
  int2*  cv       = (int2*)(bbase + 256);                // NE packed (col,val)
  const size_t need = (size_t)(2 * NN * DIM) * 4 + (size_t)(3 * NN + 2 + 512) * 4 + (size_t)NE * 8;

  const dim3 blk(256);
  const int g128 = (NN + 63) / 64;
  const int g64  = (NN + 127) / 128;

  if (ws_size >= need) {
    // ---- build CSR once, reuse 3x ----
    hipMemsetAsync(cnt, 0, (size_t)NN * 4, stream);
    edge_histo<<<(NE + 255) / 256, blk, 0, stream>>>(ei, cnt);
    block_sums<<<NB, blk, 0, stream>>>(cnt, bsum);
    scan_bsums<<<1, blk, 0, stream>>>(bsum, bbase);
    scan_final<<<NB, blk, 0, stream>>>(cnt, bbase, rowStart, cursor);
    edge_scatter<<<(NE + 255) / 256, blk, 0, stream>>>(ei, C, cursor, cv);

    // layer 1: prop = C@x; h = norm(relu(prop@W1 + b1))
    spmm_csr<128, false><<<(NN + 7) / 8, blk, 0, stream>>>(rowStart, cv, x, nullptr, prop);
    gemm_rt<128, true, true><<<g128, blk, 0, stream>>>(prop, W1, b1, h, NN);
    // layer 2
    spmm_csr<128, false><<<(NN + 7) / 8, blk, 0, stream>>>(rowStart, cv, h, nullptr, prop);
    gemm_rt<128, true, true><<<g128, blk, 0, stream>>>(prop, W2, b2, h, NN);
    // layer 3 reassociated: g = h@W3 (no bias); out = C@g + b3
    gemm_rt<64, false, false><<<g64, blk, 0, stream>>>(h, W3, nullptr, prop, NN);
    spmm_csr<64, true><<<(NN + 15) / 16, blk, 0, stream>>>(rowStart, cv, prop, b3, out);
  } else {
    // fallback: atomic scatter path
    const size_t propBytes = (size_t)NN * DIM * sizeof(float);
    const int spmmGrid = 4096;
    hipMemsetAsync(prop, 0, propBytes, stream);
    spmm_atomic<<<spmmGrid, blk, 0, stream>>>(ei, C, x, prop);
    gemm_rt<128, true, true><<<g128, blk, 0, stream>>>(prop, W1, b1, h, NN);
    hipMemsetAsync(prop, 0, propBytes, stream);
    spmm_atomic<<<spmmGrid, blk, 0, stream>>>(ei, C, h, prop);
    gemm_rt<128, true, true><<<g128, blk, 0, stream>>>(prop, W2, b2, h, NN);
    hipMemsetAsync(prop, 0, propBytes, stream);
    spmm_atomic<<<spmmGrid, blk, 0, stream>>>(ei, C, h, prop);
    gemm_rt<64, false, true><<<g64, blk, 0, stream>>>(prop, W3, b3, out, NN);
  }
}

// Round 7
// 407.587 us; speedup vs baseline: 10.6353x; 1.0168x over previous
//
#include <hip/hip_runtime.h>

#define NN 50000
#define NE 800000
#define DIM 128
#define NB ((NN + 255) / 256)   // 196 scan chunks

// ================= CSR build (edge pattern reused for all 3 layers) =================
__global__ __launch_bounds__(256) void edge_histo(const int* __restrict__ ei,
                                                  int* __restrict__ cnt) {
  int e = blockIdx.x * 256 + threadIdx.x;
  if (e >= NE) return;
  int r = ei[e], c = ei[NE + e];
  if ((unsigned)r < NN && (unsigned)c < NN) atomicAdd(&cnt[r], 1);
}

// ---- distributed 2-level exclusive scan ----
__global__ __launch_bounds__(256) void block_sums(const int* __restrict__ cnt,
                                                  int* __restrict__ bsum) {
  int i = blockIdx.x * 256 + threadIdx.x;
  int v = (i < NN) ? cnt[i] : 0;
#pragma unroll
  for (int off = 1; off < 64; off <<= 1) v += __shfl_xor(v, off, 64);
  __shared__ int ws[4];
  if ((threadIdx.x & 63) == 0) ws[threadIdx.x >> 6] = v;
  __syncthreads();
  if (threadIdx.x == 0) bsum[blockIdx.x] = ws[0] + ws[1] + ws[2] + ws[3];
}

__global__ __launch_bounds__(256) void scan_bsums(const int* __restrict__ bsum,
                                                  int* __restrict__ bbase) {
  int t = threadIdx.x;
  int v = (t < NB) ? bsum[t] : 0;
  int lane = t & 63, w = t >> 6;
  int inc = v;
#pragma unroll
  for (int off = 1; off < 64; off <<= 1) {
    int u = __shfl_up(inc, off, 64);
    if (lane >= off) inc += u;
  }
  __shared__ int ws[4];
  if (lane == 63) ws[w] = inc;
  __syncthreads();
  int wb = 0;
  for (int k = 0; k < w; ++k) wb += ws[k];
  if (t < NB) bbase[t] = wb + inc - v;
}

__global__ __launch_bounds__(256) void scan_final(const int* __restrict__ cnt,
                                                  const int* __restrict__ bbase,
                                                  int* __restrict__ rowStart,
                                                  int* __restrict__ cursor) {
  int i = blockIdx.x * 256 + threadIdx.x;
  int v = (i < NN) ? cnt[i] : 0;
  int lane = threadIdx.x & 63, w = threadIdx.x >> 6;
  int inc = v;
#pragma unroll
  for (int off = 1; off < 64; off <<= 1) {
    int u = __shfl_up(inc, off, 64);
    if (lane >= off) inc += u;
  }
  __shared__ int ws[4];
  if (lane == 63) ws[w] = inc;
  __syncthreads();
  int wb = 0;
  for (int k = 0; k < w; ++k) wb += ws[k];
  int ex = bbase[blockIdx.x] + wb + inc - v;   // global exclusive prefix
  if (i < NN) { rowStart[i] = ex; cursor[i] = ex; }
  if (i == NN - 1) rowStart[NN] = ex + v;
}

// Scatter packed (col, val) into row-sorted order.
__global__ __launch_bounds__(256) void edge_scatter(const int* __restrict__ ei,
                                                    const float* __restrict__ vals,
                                                    int* __restrict__ cursor,
                                                    int2* __restrict__ cv) {
  int e = blockIdx.x * 256 + threadIdx.x;
  if (e >= NE) return;
  int r = ei[e], c = ei[NE + e];
  if ((unsigned)r >= NN || (unsigned)c >= NN) return;
  int pos = atomicAdd(&cursor[r], 1);
  cv[pos] = make_int2(c, __float_as_int(vals[e]));
}

// ============ SpMM gather: D/4 lanes per row, regs accumulate, no atomics ============
template <int D, bool BIAS>
__global__ __launch_bounds__(256) void spmm_csr(const int* __restrict__ rowStart,
                                                const int2* __restrict__ cv,
                                                const float* __restrict__ h,
                                                const float* __restrict__ bias,
                                                float* __restrict__ out) {
  constexpr int L = D / 4;                      // lanes per row
  const int lane = threadIdx.x % L;
  const int r = blockIdx.x * (256 / L) + threadIdx.x / L;
  if (r >= NN) return;
  int p = rowStart[r], pend = rowStart[r + 1];
  float4 acc = BIAS ? ((const float4*)bias)[lane] : make_float4(0.f, 0.f, 0.f, 0.f);
  for (; p + 3 < pend; p += 4) {
    int2 e0 = cv[p], e1 = cv[p + 1], e2 = cv[p + 2], e3 = cv[p + 3];
    float4 x0 = ((const float4*)(h + (size_t)e0.x * D))[lane];
    float4 x1 = ((const float4*)(h + (size_t)e1.x * D))[lane];
    float4 x2 = ((const float4*)(h + (size_t)e2.x * D))[lane];
    float4 x3 = ((const float4*)(h + (size_t)e3.x * D))[lane];
    float v0 = __int_as_float(e0.y), v1 = __int_as_float(e1.y);
    float v2 = __int_as_float(e2.y), v3 = __int_as_float(e3.y);
    acc.x = fmaf(v0, x0.x, acc.x); acc.y = fmaf(v0, x0.y, acc.y);
    acc.z = fmaf(v0, x0.z, acc.z); acc.w = fmaf(v0, x0.w, acc.w);
    acc.x = fmaf(v1, x1.x, acc.x); acc.y = fmaf(v1, x1.y, acc.y);
    acc.z = fmaf(v1, x1.z, acc.z); acc.w = fmaf(v1, x1.w, acc.w);
    acc.x = fmaf(v2, x2.x, acc.x); acc.y = fmaf(v2, x2.y, acc.y);
    acc.z = fmaf(v2, x2.z, acc.z); acc.w = fmaf(v2, x2.w, acc.w);
    acc.x = fmaf(v3, x3.x, acc.x); acc.y = fmaf(v3, x3.y, acc.y);
    acc.z = fmaf(v3, x3.z, acc.z); acc.w = fmaf(v3, x3.w, acc.w);
  }
  for (; p < pend; ++p) {
    int2 e0 = cv[p];
    float v0 = __int_as_float(e0.y);
    float4 x0 = ((const float4*)(h + (size_t)e0.x * D))[lane];
    acc.x = fmaf(v0, x0.x, acc.x); acc.y = fmaf(v0, x0.y, acc.y);
    acc.z = fmaf(v0, x0.z, acc.z); acc.w = fmaf(v0, x0.w, acc.w);
  }
  ((float4*)(out + (size_t)r * D))[lane] = acc;
}

// ---------------- fallback: atomic scatter SpMM (if ws too small) ----------------
__global__ __launch_bounds__(256) void spmm_atomic(
    const int* __restrict__ ei, const float* __restrict__ vals,
    const float* __restrict__ h, float* __restrict__ prop) {
  const int lane32 = threadIdx.x & 31;
  int hw = blockIdx.x * (blockDim.x >> 5) + (threadIdx.x >> 5);
  const int stride = gridDim.x * (blockDim.x >> 5);
  for (int e = hw; e < NE; e += stride) {
    int r = ei[e], c = ei[NE + e];
    float v = vals[e];
    if ((unsigned)r >= NN || (unsigned)c >= NN) continue;
    float4 x = ((const float4*)(h + (size_t)c * DIM))[lane32];
    float* pp = prop + (size_t)r * DIM + lane32 * 4;
    unsafeAtomicAdd(pp + 0, v * x.x);
    unsafeAtomicAdd(pp + 1, v * x.y);
    unsafeAtomicAdd(pp + 2, v * x.z);
    unsafeAtomicAdd(pp + 3, v * x.w);
  }
}

// ========== Register-tiled dense layer: out = A@W (+b) (+ReLU +L2 row-norm) ==========
// MR=4/2 + launch_bounds(256,4): more blocks (TILE_M=32 -> 1563) and a 128-VGPR
// budget so the unroll-2 load window stays in flight (VGPR=64 serialized loads, R5).
template <int OUT_DIM, int MR, bool NORM, bool BIAS>
__global__ __launch_bounds__(256, 4) void gemm_rt(
    const float* __restrict__ A, const float* __restrict__ W,
    const float* __restrict__ b, float* __restrict__ out, int n) {
  constexpr int JT = OUT_DIM / 4;     // threads along N (32 or 16)
  constexpr int RG = 256 / JT;        // row groups (8 or 16)
  constexpr int TILE_M = RG * MR;
  const int j  = threadIdx.x % JT;
  const int rg = threadIdx.x / JT;
  const int row0 = blockIdx.x * TILE_M + rg * MR;

  float4 bv = make_float4(0.f, 0.f, 0.f, 0.f);
  if (BIAS) bv = ((const float4*)b)[j];

  float acc[MR][4];
#pragma unroll
  for (int i = 0; i < MR; ++i) {
    acc[i][0] = bv.x; acc[i][1] = bv.y; acc[i][2] = bv.z; acc[i][3] = bv.w;
  }
  const float* Arow[MR];
#pragma unroll
  for (int i = 0; i < MR; ++i) {
    int r = row0 + i; if (r > n - 1) r = n - 1;
    Arow[i] = A + (size_t)r * DIM;
  }

#pragma unroll 2
  for (int kk = 0; kk < DIM; kk += 4) {
    float4 w0 = *(const float4*)(W + (size_t)(kk + 0) * OUT_DIM + j * 4);
    float4 w1 = *(const float4*)(W + (size_t)(kk + 1) * OUT_DIM + j * 4);
    float4 w2 = *(const float4*)(W + (size_t)(kk + 2) * OUT_DIM + j * 4);
    float4 w3 = *(const float4*)(W + (size_t)(kk + 3) * OUT_DIM + j * 4);
    float4 a4[MR];
#pragma unroll
    for (int i = 0; i < MR; ++i) a4[i] = *(const float4*)(Arow[i] + kk);
#pragma unroll
    for (int i = 0; i < MR; ++i) {
      acc[i][0] = fmaf(a4[i].x, w0.x, acc[i][0]);
      acc[i][1] = fmaf(a4[i].x, w0.y, acc[i][1]);
      acc[i][2] = fmaf(a4[i].x, w0.z, acc[i][2]);
      acc[i][3] = fmaf(a4[i].x, w0.w, acc[i][3]);
      acc[i][0] = fmaf(a4[i].y, w1.x, acc[i][0]);
      acc[i][1] = fmaf(a4[i].y, w1.y, acc[i][1]);
      acc[i][2] = fmaf(a4[i].y, w1.z, acc[i][2]);
      acc[i][3] = fmaf(a4[i].y, w1.w, acc[i][3]);
      acc[i][0] = fmaf(a4[i].z, w2.x, acc[i][0]);
      acc[i][1] = fmaf(a4[i].z, w2.y, acc[i][1]);
      acc[i][2] = fmaf(a4[i].z, w2.z, acc[i][2]);
      acc[i][3] = fmaf(a4[i].z, w2.w, acc[i][3]);
      acc[i][0] = fmaf(a4[i].w, w3.x, acc[i][0]);
      acc[i][1] = fmaf(a4[i].w, w3.y, acc[i][1]);
      acc[i][2] = fmaf(a4[i].w, w3.z, acc[i][2]);
      acc[i][3] = fmaf(a4[i].w, w3.w, acc[i][3]);
    }
  }

#pragma unroll
  for (int i = 0; i < MR; ++i) {
    int row = row0 + i;
    if (NORM) {
      float v0 = fmaxf(acc[i][0], 0.f), v1 = fmaxf(acc[i][1], 0.f);
      float v2 = fmaxf(acc[i][2], 0.f), v3 = fmaxf(acc[i][3], 0.f);
      float s = v0 * v0 + v1 * v1 + v2 * v2 + v3 * v3;
#pragma unroll
      for (int off = JT / 2; off >= 1; off >>= 1) s += __shfl_xor(s, off, JT);
      float inv = 1.0f / fmaxf(sqrtf(s), 1e-12f);
      if (row < n) {
        float4 st = make_float4(v0 * inv, v1 * inv, v2 * inv, v3 * inv);
        ((float4*)(out + (size_t)row * OUT_DIM))[j] = st;
      }
    } else {
      if (row < n) {
        float4 st = make_float4(acc[i][0], acc[i][1], acc[i][2], acc[i][3]);
        ((float4*)(out + (size_t)row * OUT_DIM))[j] = st;
      }
    }
  }
}

extern "C" void kernel_launch(void* const* d_in, const int* in_sizes, int n_in,
                              void* d_out, int out_size, void* d_ws, size_t ws_size,
                              hipStream_t stream) {
  const float* x  = (const float*)d_in[0];
  const int*   ei = (const int*)d_in[1];
  const float* C  = (const float*)d_in[2];
  const float* W1 = (const float*)d_in[3];
  const float* b1 = (const float*)d_in[4];
  const float* W2 = (const float*)d_in[5];
  const float* b2 = (const float*)d_in[6];
  const float* W3 = (const float*)d_in[7];
  const float* b3 = (const float*)d_in[8];
  float* out = (float*)d_out;

  // ---- workspace layout ----
  float* prop     = (float*)d_ws;                        // NN*DIM f32 (also g[NN*64])
  float* h        = prop + (size_t)NN * DIM;             // NN*DIM f32
  int*   rowStart = (int*)(h + (size_t)NN * DIM);        // NN+1 (+pad)
  int*   cnt      = rowStart + NN + 2;                   // NN
  int*   cursor   = cnt + NN;                            // NN
  int*   bsum     = cursor + NN;                         // 256
  int*   bbase    = bsum + 256;                          // 256
  int2*  cv       = (int2*)(bbase + 256);                // NE packed (col,val)
  const size_t need = (size_t)(2 * NN * DIM) * 4 + (size_t)(3 * NN + 2 + 512) * 4 + (size_t)NE * 8;

  const dim3 blk(256);
  const int g128 = (NN + 31) / 32;   // gemm_rt<128,4> tiles 32 rows
  const int g64  = (NN + 31) / 32;   // gemm_rt<64,2>  tiles 32 rows

  if (ws_size >= need) {
    // ---- build CSR once, reuse 3x ----
    hipMemsetAsync(cnt, 0, (size_t)NN * 4, stream);
    edge_histo<<<(NE + 255) / 256, blk, 0, stream>>>(ei, cnt);
    block_sums<<<NB, blk, 0, stream>>>(cnt, bsum);
    scan_bsums<<<1, blk, 0, stream>>>(bsum, bbase);
    scan_final<<<NB, blk, 0, stream>>>(cnt, bbase, rowStart, cursor);
    edge_scatter<<<(NE + 255) / 256, blk, 0, stream>>>(ei, C, cursor, cv);

    // layer 1: prop = C@x; h = norm(relu(prop@W1 + b1))
    spmm_csr<128, false><<<(NN + 7) / 8, blk, 0, stream>>>(rowStart, cv, x, nullptr, prop);
    gemm_rt<128, 4, true, true><<<g128, blk, 0, stream>>>(prop, W1, b1, h, NN);
    // layer 2
    spmm_csr<128, false><<<(NN + 7) / 8, blk, 0, stream>>>(rowStart, cv, h, nullptr, prop);
    gemm_rt<128, 4, true, true><<<g128, blk, 0, stream>>>(prop, W2, b2, h, NN);
    // layer 3 reassociated: g = h@W3 (no bias); out = C@g + b3
    gemm_rt<64, 2, false, false><<<g64, blk, 0, stream>>>(h, W3, nullptr, prop, NN);
    spmm_csr<64, true><<<(NN + 15) / 16, blk, 0, stream>>>(rowStart, cv, prop, b3, out);
  } else {
    // fallback: atomic scatter path
    const size_t propBytes = (size_t)NN * DIM * sizeof(float);
    const int spmmGrid = 4096;
    hipMemsetAsync(prop, 0, propBytes, stream);
    spmm_atomic<<<spmmGrid, blk, 0, stream>>>(ei, C, x, prop);
    gemm_rt<128, 4, true, true><<<g128, blk, 0, stream>>>(prop, W1, b1, h, NN);
    hipMemsetAsync(prop, 0, propBytes, stream);
    spmm_atomic<<<spmmGrid, blk, 0, stream>>>(ei, C, h, prop);
    gemm_rt<128, 4, true, true><<<g128, blk, 0, stream>>>(prop, W2, b2, h, NN);
    hipMemsetAsync(prop, 0, propBytes, stream);
    spmm_atomic<<<spmmGrid, blk, 0, stream>>>(ei, C, h, prop);
    gemm_rt<64, 2, false, true><<<g64, blk, 0, stream>>>(prop, W3, b3, out, NN);
  }
}